// Round 5
// baseline (197.803 us; speedup 1.0000x reference)
//
#include <hip/hip_runtime.h>
#include <hip/hip_bf16.h>

typedef short s16x8 __attribute__((ext_vector_type(8)));
typedef float f32x4 __attribute__((ext_vector_type(4)));
typedef float f32x2 __attribute__((ext_vector_type(2)));
typedef unsigned int u32x4 __attribute__((ext_vector_type(4)));

constexpr int Bb = 2, NQ = 13294, Hh = 8, HD = 32;
constexpr int Mrows = Bb * NQ; // 26588

__device__ inline short bf16_of(float f) {
  __hip_bfloat16 h = __float2bfloat16(f);
  return *reinterpret_cast<short*>(&h);
}

// Strip-looped GEMM: grid = 416 row-panels; each block computes 64 rows x NS*64 cols.
// A is fetched from HBM exactly once; W strips re-read from L2 (small, resident).
// MODE 0: bf16 scatter to vproj[B][H][NQ][HD]   (NS=4, W=Wv)
// MODE 1: fused query GEMM (NS=6): s<4 -> Wso (N=256) at offaw[row*384+col],
//         s>=4 -> Waw (N=128) at offaw[row*384+256+col]
// MODE 3: fp32 linear stride 256 to d_out      (NS=4, A bf16)
template<int MODE, int NS, bool ABF16>
__global__ __launch_bounds__(256) void gemm_k(
    const void* __restrict__ Araw, const float* __restrict__ W,
    const float* __restrict__ bias, void* __restrict__ outraw,
    const float* __restrict__ W2, const float* __restrict__ bias2)
{
  __shared__ short As[64][40];        // +8 pad breaks bank conflicts on ds_read_b128
  __shared__ short Bs[NS][64][40];    // Bs[s][n][k]
  const int row0 = blockIdx.x * 64;
  const int tid = threadIdx.x;
  const int lane = tid & 63, wave = tid >> 6;

  f32x4 acc[NS][4] = {};
  const int ar = tid >> 2, ak = (tid & 3) * 8;   // A stage: 64 rows x 32 k
  int grow = row0 + ar; if (grow >= Mrows) grow = Mrows - 1;
  const int kk = tid & 31, nb = (tid >> 5) * 8;  // B stage: transpose on write

  for (int kt = 0; kt < 256; kt += 32) {
    s16x8 av;
    if constexpr (ABF16) {
      av = *(const s16x8*)((const short*)Araw + (size_t)grow * 256 + kt + ak);
    } else {
      const float* A = (const float*)Araw;
      f32x4 a0 = *(const f32x4*)(A + (size_t)grow * 256 + kt + ak);
      f32x4 a1 = *(const f32x4*)(A + (size_t)grow * 256 + kt + ak + 4);
#pragma unroll
      for (int i = 0; i < 4; i++) { av[i] = bf16_of(a0[i]); av[4 + i] = bf16_of(a1[i]); }
    }
    *(s16x8*)(&As[ar][ak]) = av;

#pragma unroll
    for (int s = 0; s < NS; s++) {
      const float* Wp = W; int Nw = 256, cb = s * 64;
      if (MODE == 1 && s >= 4) { Wp = W2; Nw = 128; cb = (s - 4) * 64; }
      f32x4 w0 = *(const f32x4*)(Wp + (size_t)(kt + kk) * Nw + cb + nb);
      f32x4 w1 = *(const f32x4*)(Wp + (size_t)(kt + kk) * Nw + cb + nb + 4);
#pragma unroll
      for (int i = 0; i < 4; i++) { Bs[s][nb + i][kk] = bf16_of(w0[i]); Bs[s][nb + 4 + i][kk] = bf16_of(w1[i]); }
    }
    __syncthreads();

    s16x8 afr[4];
#pragma unroll
    for (int m = 0; m < 4; m++) afr[m] = *(const s16x8*)(&As[m * 16 + (lane & 15)][(lane >> 4) * 8]);
#pragma unroll
    for (int s = 0; s < NS; s++) {
      s16x8 bfr = *(const s16x8*)(&Bs[s][wave * 16 + (lane & 15)][(lane >> 4) * 8]);
#pragma unroll
      for (int m = 0; m < 4; m++)
        acc[s][m] = __builtin_amdgcn_mfma_f32_16x16x32_bf16(afr[m], bfr, acc[s][m], 0, 0, 0);
    }
    __syncthreads();
  }

  // D mapping: col = lane&15, row = (lane>>4)*4 + reg
#pragma unroll
  for (int s = 0; s < NS; s++) {
    const bool second = (MODE == 1 && s >= 4);
    const int colL = (second ? (s - 4) * 64 : s * 64) + wave * 16 + (lane & 15);
    const float bvf = (second ? bias2 : bias)[colL];
#pragma unroll
    for (int m = 0; m < 4; m++) {
#pragma unroll
      for (int r = 0; r < 4; r++) {
        int rowL = row0 + m * 16 + (lane >> 4) * 4 + r;
        if (rowL < Mrows) {
          float v = acc[s][m][r] + bvf;
          if constexpr (MODE == 0) {
            int b = rowL / NQ, n = rowL - (rowL / NQ) * NQ;
            int h = colL >> 5, c = colL & 31;
            ((__hip_bfloat16*)outraw)[(((size_t)b * Hh + h) * NQ + n) * HD + c] = __float2bfloat16(v);
          } else if constexpr (MODE == 1) {
            ((__hip_bfloat16*)outraw)[(size_t)rowL * 384 + (second ? 256 : 0) + colL] = __float2bfloat16(v);
          } else {
            ((float*)outraw)[(size_t)rowL * 256 + colL] = v;
          }
        }
      }
    }
  }
}

// XCD-local sampler. Block = one (b,h) plane x 64 queries; plane = blockIdx&15
// so (assuming round-robin block->XCD) each XCD gathers from only 2 planes
// (1.7 MB, fits 4 MiB L2). Corners loaded as 128B row-pairs (full granule use).
// Phase A: 4 iters x 256 threads = 1024 (q,lp) descriptor tasks, fused softmax.
// Phase B: wave owns 16 queries; per query 4 wave-loads (8 lanes per 128B pair:
// r = x-slot, c = 16B channel slice), pk-FMA accumulate, shfl-reduce over lanes.
__global__ __launch_bounds__(256) void sample_k(
    const __hip_bfloat16* __restrict__ vproj,
    const __hip_bfloat16* __restrict__ offaw,
    const float* __restrict__ refp,
    __hip_bfloat16* __restrict__ interm)
{
  __shared__ float dw[64][16][2][2];
  __shared__ int   dbase[64][16][2];
  const int plane = blockIdx.x & 15;
  const int chunk = blockIdx.x >> 4;
  const int b = plane >> 3, h = plane & 7;
  const int q0 = chunk * 64;
  const int tid = threadIdx.x;
  const int dims[4]   = {100, 50, 25, 13};
  const int starts[4] = {0, 10000, 12500, 13125};

#pragma unroll
  for (int it = 0; it < 4; it++) {
    const int task = it * 256 + tid;
    const int ql = task >> 4, lp = task & 15;
    const int l = lp >> 2;
    const int lw = dims[l];
    int q = q0 + ql; if (q >= NQ) q = NQ - 1;   // clamped: reads valid data, write guarded later
    const size_t row = (size_t)b * NQ + q;
    unsigned int oxy = *(const unsigned int*)((const unsigned short*)offaw + row * 384 + h * 32 + lp * 2);
    float offx = __uint_as_float(oxy << 16);
    float offy = __uint_as_float(oxy & 0xffff0000u);
    float logit = __bfloat162float(offaw[row * 384 + 256 + h * 16 + lp]);
    float2 rp = *(const float2*)(refp + (row * 4 + l) * 2);
    float gx = rp.x * (float)lw + offx - 0.5f;
    float gy = rp.y * (float)lw + offy - 0.5f;
    float mx = logit;
#pragma unroll
    for (int d = 1; d < 16; d <<= 1) mx = fmaxf(mx, __shfl_xor(mx, d));
    float e = __expf(logit - mx);
    float ssum = e;
#pragma unroll
    for (int d = 1; d < 16; d <<= 1) ssum += __shfl_xor(ssum, d);
    float aw = e / ssum;

    float xf = floorf(gx), yf = floorf(gy);
    int x0 = (int)xf, y0 = (int)yf;
    float wx = gx - xf, wy = gy - yf;
    int bx = min(max(x0, 0), lw - 2);
    bool lxv = (x0 >= 0) & (x0 < lw);
    bool rxv = (x0 + 1 >= 0) & (x0 + 1 < lw);
    float wl = 1.f - wx, wr = wx;
    // weight of x-slot r (absolute x = bx + r): sum of matching valid corners
    float ws0 = (lxv && x0 == bx     ? wl : 0.f) + (rxv && x0 + 1 == bx     ? wr : 0.f);
    float ws1 = (lxv && x0 == bx + 1 ? wl : 0.f) + (rxv && x0 + 1 == bx + 1 ? wr : 0.f);
    const int pbase = (b * Hh + h) * NQ + starts[l];
#pragma unroll
    for (int yi = 0; yi < 2; yi++) {
      int yc = y0 + yi;
      bool yv = (yc >= 0) & (yc < lw);
      int ycl = min(max(yc, 0), lw - 1);
      float wyt = (yi ? wy : 1.f - wy) * aw * (yv ? 1.f : 0.f);
      dw[ql][lp][yi][0] = ws0 * wyt;
      dw[ql][lp][yi][1] = ws1 * wyt;
      dbase[ql][lp][yi] = pbase + ycl * lw + bx;
    }
  }
  __syncthreads();

  const int wv = tid >> 6, lane = tid & 63;
  const int g = lane >> 3, r = (lane >> 2) & 1, c = lane & 3;
  for (int qi = 0; qi < 16; qi++) {
    const int ql = wv * 16 + qi;
    f32x2 a2[4] = {};
#pragma unroll
    for (int t = 0; t < 4; t++) {
      const int combo = t * 8 + g;
      const int s = combo & 15, yi = combo >> 4;
      const int base = dbase[ql][s][yi];
      const float w = dw[ql][s][yi][r];
      const u32x4 u = *(const u32x4*)((const char*)vproj + (((size_t)(base + r)) << 6) + c * 16);
      const f32x2 wb = {w, w};
#pragma unroll
      for (int j = 0; j < 4; j++) {
        f32x2 v2 = { __uint_as_float(u[j] << 16), __uint_as_float(u[j] & 0xffff0000u) };
        a2[j] += v2 * wb;
      }
    }
#pragma unroll
    for (int m = 4; m <= 32; m <<= 1) {
#pragma unroll
      for (int j = 0; j < 4; j++) {
        a2[j][0] += __shfl_xor(a2[j][0], m);
        a2[j][1] += __shfl_xor(a2[j][1], m);
      }
    }
    const int q = q0 + ql;
    if (lane < 4 && q < NQ) {
      unsigned int up[4];
#pragma unroll
      for (int j = 0; j < 4; j++) {
        unsigned int b0 = (unsigned int)(unsigned short)bf16_of(a2[j][0]);
        unsigned int b1 = (unsigned int)(unsigned short)bf16_of(a2[j][1]);
        up[j] = (b1 << 16) | b0;
      }
      u32x4 pk = { up[0], up[1], up[2], up[3] };
      *(u32x4*)((unsigned short*)interm + ((size_t)b * NQ + q) * 256 + h * 32 + c * 8) = pk;
    }
  }
}

extern "C" void kernel_launch(void* const* d_in, const int* in_sizes, int n_in,
                              void* d_out, int out_size, void* d_ws, size_t ws_size,
                              hipStream_t stream)
{
  const float* query = (const float*)d_in[0];
  const float* refp  = (const float*)d_in[1];
  const float* value = (const float*)d_in[2];
  // d_in[3] = spatial_shapes (static, hardcoded)
  const float* Wso = (const float*)d_in[4];
  const float* bso = (const float*)d_in[5];
  const float* Waw = (const float*)d_in[6];
  const float* baw = (const float*)d_in[7];
  const float* Wv  = (const float*)d_in[8];
  const float* bv  = (const float*)d_in[9];
  const float* Wo  = (const float*)d_in[10];
  const float* bo  = (const float*)d_in[11];

  char* ws = (char*)d_ws;
  __hip_bfloat16* vproj  = (__hip_bfloat16*)ws;                 // 13,613,056 B (+ slack below)
  __hip_bfloat16* offaw  = (__hip_bfloat16*)(ws + 13614080);    // 20,419,584 B
  __hip_bfloat16* interm = (__hip_bfloat16*)(ws + 34034688);    // 13,613,056 B
  float* out = (float*)d_out;

  dim3 blk(256);
  gemm_k<0, 4, false><<<dim3(416), blk, 0, stream>>>(value, Wv, bv, vproj, nullptr, nullptr);
  gemm_k<1, 6, false><<<dim3(416), blk, 0, stream>>>(query, Wso, bso, offaw, Waw, baw);
  sample_k<<<dim3(16 * 208), blk, 0, stream>>>(vproj, offaw, refp, interm);
  gemm_k<3, 4, true><<<dim3(416), blk, 0, stream>>>(interm, Wo, bo, out, nullptr, nullptr);
}

// Round 6
// 196.544 us; speedup vs baseline: 1.0064x; 1.0064x over previous
//
#include <hip/hip_runtime.h>
#include <hip/hip_bf16.h>
#include <hip/hip_fp16.h>

typedef short s16x8 __attribute__((ext_vector_type(8)));
typedef float f32x4 __attribute__((ext_vector_type(4)));
typedef float f32x2 __attribute__((ext_vector_type(2)));
typedef unsigned int u32x4 __attribute__((ext_vector_type(4)));
typedef unsigned int u32x2 __attribute__((ext_vector_type(2)));

constexpr int Bb = 2, NQ = 13294, Hh = 8, HD = 32;
constexpr int Mrows = Bb * NQ; // 26588

__device__ inline short bf16_of(float f) {
  __hip_bfloat16 h = __float2bfloat16(f);
  return *reinterpret_cast<short*>(&h);
}

// One-time weight prep: WT[n][k] = bf16(W[k][n]) for Wv, {Wso|Waw} fused, Wo;
// bq = concat(bso, baw) fp32. 229,376 tasks = 896 blocks x 256.
__global__ __launch_bounds__(256) void prep_k(
    const float* __restrict__ Wv, const float* __restrict__ Wso,
    const float* __restrict__ Waw, const float* __restrict__ Wo,
    const float* __restrict__ bso, const float* __restrict__ baw,
    short* __restrict__ WvT, short* __restrict__ WqT, short* __restrict__ WoT,
    float* __restrict__ bq)
{
  const int id = blockIdx.x * 256 + threadIdx.x;
  if (id < 384) bq[id] = id < 256 ? bso[id] : baw[id - 256];
  if (id < 65536) {
    int n = id >> 8, k = id & 255;
    WvT[id] = bf16_of(Wv[k * 256 + n]);
  } else if (id < 163840) {
    int t = id - 65536, n = t >> 8, k = t & 255;
    WqT[t] = bf16_of(n < 256 ? Wso[k * 256 + n] : Waw[k * 128 + (n - 256)]);
  } else {
    int t = id - 163840, n = t >> 8, k = t & 255;
    WoT[t] = bf16_of(Wo[k * 256 + n]);
  }
}

// No-LDS, no-barrier GEMM: C = A[M,256] @ WT^T + bias.
// Wave = 16 rows x 64 cols; A-frag straight from global (coalesced 128B/row
// across the 4 k-groups), B-frag straight from bf16 WT[n][k] (L1-resident).
// Grid (colTiles, 416 rowPanels) -> 1664+ blocks, latency hidden by occupancy.
// MODE 0: A fp32 -> bf16 scatter vproj[B][H][NQ][HD]
// MODE 1: A fp32 -> bf16 offaw[row*384 + col] (fused Wso|Waw, 6 col tiles)
// MODE 3: A bf16 -> fp32 out[row*256 + col]
template<int MODE>
__global__ __launch_bounds__(256) void gemm2(
    const void* __restrict__ Araw, const short* __restrict__ WT,
    const float* __restrict__ bias, void* __restrict__ outraw)
{
  const int tid = threadIdx.x, lane = tid & 63, wave = tid >> 6;
  const int col0 = blockIdx.x * 64;
  const int wrow = blockIdx.y * 64 + wave * 16;
  const int fr = lane & 15, kg = lane >> 4;
  const int arow = min(wrow + fr, Mrows - 1);
  f32x4 acc[4] = {};

#pragma unroll
  for (int kt = 0; kt < 256; kt += 32) {
    s16x8 afr;
    if constexpr (MODE == 3) {
      afr = *(const s16x8*)((const short*)Araw + (size_t)arow * 256 + kt + kg * 8);
    } else {
      const float* A = (const float*)Araw;
      f32x4 a0 = *(const f32x4*)(A + (size_t)arow * 256 + kt + kg * 8);
      f32x4 a1 = *(const f32x4*)(A + (size_t)arow * 256 + kt + kg * 8 + 4);
#pragma unroll
      for (int i = 0; i < 4; i++) { afr[i] = bf16_of(a0[i]); afr[4 + i] = bf16_of(a1[i]); }
    }
#pragma unroll
    for (int n = 0; n < 4; n++) {
      s16x8 bfr = *(const s16x8*)(WT + (size_t)(col0 + n * 16 + fr) * 256 + kt + kg * 8);
      acc[n] = __builtin_amdgcn_mfma_f32_16x16x32_bf16(afr, bfr, acc[n], 0, 0, 0);
    }
  }

  // D mapping (verified): col = lane&15 (B index), row = kg*4 + reg (A side)
#pragma unroll
  for (int n = 0; n < 4; n++) {
    const int colL = col0 + n * 16 + fr;
    const float bvf = bias[colL];
#pragma unroll
    for (int r = 0; r < 4; r++) {
      const int rowL = wrow + kg * 4 + r;
      if (rowL < Mrows) {
        float v = acc[n][r] + bvf;
        if constexpr (MODE == 0) {
          int b = rowL >= NQ, nn = rowL - b * NQ;
          int h = colL >> 5, c = colL & 31;
          ((__hip_bfloat16*)outraw)[(((size_t)b * Hh + h) * NQ + nn) * HD + c] = __float2bfloat16(v);
        } else if constexpr (MODE == 1) {
          ((__hip_bfloat16*)outraw)[(size_t)rowL * 384 + colL] = __float2bfloat16(v);
        } else {
          ((float*)outraw)[(size_t)rowL * 256 + colL] = v;
        }
      }
    }
  }
}

// XCD-local sampler, paired-query phase B.
// Block = one (b,h) plane x 64 queries; plane = blockIdx&15 -> each XCD's L2
// holds ~2 planes (1.7MB). Descriptors packed 8B: {base:int, half2(w0,w1)}.
// Phase B: wave owns 16 queries, processed as 8 pairs (lane>>5 = query half);
// per pair 8 divergent 16B gathers in flight, then 3-round shfl reduce.
__global__ __launch_bounds__(256) void sample_k(
    const __hip_bfloat16* __restrict__ vproj,
    const __hip_bfloat16* __restrict__ offaw,
    const float* __restrict__ refp,
    __hip_bfloat16* __restrict__ interm)
{
  __shared__ u32x2 dpack[64][16][2];   // 16 KB
  const int plane = blockIdx.x & 15;
  const int chunk = blockIdx.x >> 4;
  const int b = plane >> 3, h = plane & 7;
  const int q0 = chunk * 64;
  const int tid = threadIdx.x;
  const int dims[4]   = {100, 50, 25, 13};
  const int starts[4] = {0, 10000, 12500, 13125};

#pragma unroll
  for (int it = 0; it < 4; it++) {
    const int task = it * 256 + tid;
    const int ql = task >> 4, lp = task & 15;
    const int l = lp >> 2;
    const int lw = dims[l];
    int q = q0 + ql; if (q >= NQ) q = NQ - 1;   // clamped read; write guarded later
    const size_t row = (size_t)b * NQ + q;
    unsigned int oxy = *(const unsigned int*)((const unsigned short*)offaw + row * 384 + h * 32 + lp * 2);
    float offx = __uint_as_float(oxy << 16);
    float offy = __uint_as_float(oxy & 0xffff0000u);
    float logit = __bfloat162float(offaw[row * 384 + 256 + h * 16 + lp]);
    float2 rp = *(const float2*)(refp + (row * 4 + l) * 2);
    float gx = rp.x * (float)lw + offx - 0.5f;
    float gy = rp.y * (float)lw + offy - 0.5f;
    float mx = logit;
#pragma unroll
    for (int d = 1; d < 16; d <<= 1) mx = fmaxf(mx, __shfl_xor(mx, d));
    float e = __expf(logit - mx);
    float ssum = e;
#pragma unroll
    for (int d = 1; d < 16; d <<= 1) ssum += __shfl_xor(ssum, d);
    float aw = e / ssum;

    float xf = floorf(gx), yf = floorf(gy);
    int x0 = (int)xf, y0 = (int)yf;
    float wx = gx - xf, wy = gy - yf;
    int bx = min(max(x0, 0), lw - 2);
    bool lxv = (x0 >= 0) & (x0 < lw);
    bool rxv = (x0 + 1 >= 0) & (x0 + 1 < lw);
    float wl = 1.f - wx, wr = wx;
    float ws0 = (lxv && x0 == bx     ? wl : 0.f) + (rxv && x0 + 1 == bx     ? wr : 0.f);
    float ws1 = (lxv && x0 == bx + 1 ? wl : 0.f) + (rxv && x0 + 1 == bx + 1 ? wr : 0.f);
    const int pbase = (b * Hh + h) * NQ + starts[l];
#pragma unroll
    for (int yi = 0; yi < 2; yi++) {
      int yc = y0 + yi;
      bool yv = (yc >= 0) & (yc < lw);
      int ycl = min(max(yc, 0), lw - 1);
      float wyt = (yi ? wy : 1.f - wy) * aw * (yv ? 1.f : 0.f);
      __half h0 = __float2half(ws0 * wyt);
      __half h1 = __float2half(ws1 * wyt);
      unsigned int pw = (unsigned int)(*(unsigned short*)&h0)
                      | ((unsigned int)(*(unsigned short*)&h1) << 16);
      u32x2 pk; pk[0] = (unsigned int)(pbase + ycl * lw + bx); pk[1] = pw;
      dpack[ql][lp][yi] = pk;
    }
  }
  __syncthreads();

  const int wv = tid >> 6, lane = tid & 63;
  const int qh = lane >> 5, g2 = (lane >> 3) & 3, r = (lane >> 2) & 1, c = lane & 3;
  for (int p = 0; p < 8; p++) {
    const int ql = wv * 16 + p * 2 + qh;
    f32x2 a2[4] = {};
#pragma unroll
    for (int t = 0; t < 8; t++) {
      const int combo = t * 4 + g2;
      const int s = combo & 15, yi = combo >> 4;
      const u32x2 d = dpack[ql][s][yi];
      unsigned short hw = (unsigned short)(r ? (d[1] >> 16) : (d[1] & 0xffffu));
      const float w = __half2float(*(const __half*)&hw);
      const u32x4 u = *(const u32x4*)((const char*)vproj + (((size_t)(d[0] + r)) << 6) + c * 16);
      const f32x2 wb = {w, w};
#pragma unroll
      for (int j = 0; j < 4; j++) {
        f32x2 v2 = { __uint_as_float(u[j] << 16), __uint_as_float(u[j] & 0xffff0000u) };
        a2[j] += v2 * wb;
      }
    }
    // reduce over r (xor 4) and g2 (xor 8, 16) within each 32-lane half
#pragma unroll
    for (int m = 4; m <= 16; m <<= 1) {
#pragma unroll
      for (int j = 0; j < 4; j++) {
        a2[j][0] += __shfl_xor(a2[j][0], m);
        a2[j][1] += __shfl_xor(a2[j][1], m);
      }
    }
    const int q = q0 + ql;
    if ((lane & 31) < 4 && q < NQ) {
      unsigned int up[4];
#pragma unroll
      for (int j = 0; j < 4; j++) {
        unsigned int b0 = (unsigned int)(unsigned short)bf16_of(a2[j][0]);
        unsigned int b1 = (unsigned int)(unsigned short)bf16_of(a2[j][1]);
        up[j] = (b1 << 16) | b0;
      }
      u32x4 pk = { up[0], up[1], up[2], up[3] };
      *(u32x4*)((unsigned short*)interm + ((size_t)b * NQ + q) * 256 + h * 32 + c * 8) = pk;
    }
  }
}

extern "C" void kernel_launch(void* const* d_in, const int* in_sizes, int n_in,
                              void* d_out, int out_size, void* d_ws, size_t ws_size,
                              hipStream_t stream)
{
  const float* query = (const float*)d_in[0];
  const float* refp  = (const float*)d_in[1];
  const float* value = (const float*)d_in[2];
  // d_in[3] = spatial_shapes (static, hardcoded)
  const float* Wso = (const float*)d_in[4];
  const float* bso = (const float*)d_in[5];
  const float* Waw = (const float*)d_in[6];
  const float* baw = (const float*)d_in[7];
  const float* Wv  = (const float*)d_in[8];
  const float* bv  = (const float*)d_in[9];
  const float* Wo  = (const float*)d_in[10];
  const float* bo  = (const float*)d_in[11];

  char* ws = (char*)d_ws;
  __hip_bfloat16* vproj  = (__hip_bfloat16*)ws;                 // 13,613,056 B
  __hip_bfloat16* offaw  = (__hip_bfloat16*)(ws + 13613056);    // 20,419,584 B
  __hip_bfloat16* interm = (__hip_bfloat16*)(ws + 34032640);    // 13,613,056 B
  short* WvT = (short*)(ws + 47645696);                         //    131,072 B
  short* WqT = (short*)(ws + 47776768);                         //    196,608 B
  short* WoT = (short*)(ws + 47973376);                         //    131,072 B
  float* bq  = (float*)(ws + 48104448);                         //      1,536 B
  float* out = (float*)d_out;

  dim3 blk(256);
  prep_k<<<dim3(896), blk, 0, stream>>>(Wv, Wso, Waw, Wo, bso, baw, WvT, WqT, WoT, bq);
  gemm2<0><<<dim3(4, 416), blk, 0, stream>>>(value, WvT, bv, vproj);
  gemm2<1><<<dim3(6, 416), blk, 0, stream>>>(query, WqT, bq, offaw);
  sample_k<<<dim3(16 * 208), blk, 0, stream>>>(vproj, offaw, refp, interm);
  gemm2<3><<<dim3(4, 416), blk, 0, stream>>>(interm, WoT, bo, out);
}

// Round 7
// 104.683 us; speedup vs baseline: 1.8895x; 1.8775x over previous
//
#include <hip/hip_runtime.h>
#include <hip/hip_bf16.h>
#include <hip/hip_fp16.h>

typedef short s16x8 __attribute__((ext_vector_type(8)));
typedef float f32x4 __attribute__((ext_vector_type(4)));
typedef float f32x2 __attribute__((ext_vector_type(2)));
typedef unsigned int u32x4 __attribute__((ext_vector_type(4)));
typedef unsigned int u32x2 __attribute__((ext_vector_type(2)));

constexpr int Bb = 2, NQ = 13294, Hh = 8, HD = 32;
constexpr int Mrows = Bb * NQ; // 26588

__device__ inline short bf16_of(float f) {
  __hip_bfloat16 h = __float2bfloat16(f);
  return *reinterpret_cast<short*>(&h);
}

// One-time weight prep: WT[n][k] = bf16(W[k][n]) for Wv, {Wso|Waw} fused, Wo;
// bq = concat(bso, baw) fp32. 229,376 tasks = 896 blocks x 256.
__global__ __launch_bounds__(256) void prep_k(
    const float* __restrict__ Wv, const float* __restrict__ Wso,
    const float* __restrict__ Waw, const float* __restrict__ Wo,
    const float* __restrict__ bso, const float* __restrict__ baw,
    short* __restrict__ WvT, short* __restrict__ WqT, short* __restrict__ WoT,
    float* __restrict__ bq)
{
  const int id = blockIdx.x * 256 + threadIdx.x;
  if (id < 384) bq[id] = id < 256 ? bso[id] : baw[id - 256];
  if (id < 65536) {
    int n = id >> 8, k = id & 255;
    WvT[id] = bf16_of(Wv[k * 256 + n]);
  } else if (id < 163840) {
    int t = id - 65536, n = t >> 8, k = t & 255;
    WqT[t] = bf16_of(n < 256 ? Wso[k * 256 + n] : Waw[k * 128 + (n - 256)]);
  } else {
    int t = id - 163840, n = t >> 8, k = t & 255;
    WoT[t] = bf16_of(Wo[k * 256 + n]);
  }
}

// LDS-staged MFMA GEMM, XCD-swizzled grid. C = A[M,256] @ WT^T + bias.
// Grid = NT*416 flat blocks; 416 row-panels = 8 XCDs x 52. xcd = wg&7 owns 52
// contiguous row-panels x NT col-tiles (col-fast) -> A panel HBM-fetched once
// per XCD, col-tile re-reads hit that XCD's L2.
// MODE 0: A fp32 -> bf16 scatter vproj[B][H][NQ][HD]   (NT=4)
// MODE 1: A fp32 -> bf16 offaw[row*384+col], fused Wso|Waw (NT=6)
// MODE 3: A bf16 -> fp32 out[row*256+col]              (NT=4)
template<int MODE, int NT>
__global__ __launch_bounds__(256) void gemm_k(
    const void* __restrict__ Araw, const short* __restrict__ WT,
    const float* __restrict__ bias, void* __restrict__ outraw)
{
  __shared__ short As[64][40];   // +8 pad
  __shared__ short Bs[64][40];   // Bs[n][k]
  const int wg = blockIdx.x;
  const int xcd = wg & 7, local = wg >> 3;
  const int row0 = (xcd * 52 + local / NT) * 64;
  const int col0 = (local % NT) * 64;
  const int tid = threadIdx.x;
  const int lane = tid & 63, wave = tid >> 6;

  f32x4 acc[4] = {};
  const int ar = tid >> 2, ak = (tid & 3) * 8;   // stage: 64 rows x 32 k, 16B/lane
  int grow = row0 + ar; if (grow >= Mrows) grow = Mrows - 1;

  for (int kt = 0; kt < 256; kt += 32) {
    s16x8 av;
    if constexpr (MODE == 3) {
      av = *(const s16x8*)((const short*)Araw + (size_t)grow * 256 + kt + ak);
    } else {
      const float* A = (const float*)Araw;
      f32x4 a0 = *(const f32x4*)(A + (size_t)grow * 256 + kt + ak);
      f32x4 a1 = *(const f32x4*)(A + (size_t)grow * 256 + kt + ak + 4);
#pragma unroll
      for (int i = 0; i < 4; i++) { av[i] = bf16_of(a0[i]); av[4 + i] = bf16_of(a1[i]); }
    }
    *(s16x8*)(&As[ar][ak]) = av;
    *(s16x8*)(&Bs[ar][ak]) = *(const s16x8*)(WT + (size_t)(col0 + ar) * 256 + kt + ak);
    __syncthreads();

    s16x8 bfr = *(const s16x8*)(&Bs[wave * 16 + (lane & 15)][(lane >> 4) * 8]);
#pragma unroll
    for (int m = 0; m < 4; m++) {
      s16x8 afr = *(const s16x8*)(&As[m * 16 + (lane & 15)][(lane >> 4) * 8]);
      acc[m] = __builtin_amdgcn_mfma_f32_16x16x32_bf16(afr, bfr, acc[m], 0, 0, 0);
    }
    __syncthreads();
  }

  // D mapping (verified): col = lane&15, row = (lane>>4)*4 + reg
  const int colL = col0 + wave * 16 + (lane & 15);
  const float bvf = bias[colL];
#pragma unroll
  for (int m = 0; m < 4; m++) {
#pragma unroll
    for (int r = 0; r < 4; r++) {
      int rowL = row0 + m * 16 + (lane >> 4) * 4 + r;
      if (rowL < Mrows) {
        float v = acc[m][r] + bvf;
        if constexpr (MODE == 0) {
          int b = rowL >= NQ, nn = rowL - b * NQ;
          int h = colL >> 5, c = colL & 31;
          ((__hip_bfloat16*)outraw)[(((size_t)b * Hh + h) * NQ + nn) * HD + c] = __float2bfloat16(v);
        } else if constexpr (MODE == 1) {
          ((__hip_bfloat16*)outraw)[(size_t)rowL * 384 + colL] = __float2bfloat16(v);
        } else {
          ((float*)outraw)[(size_t)rowL * 256 + colL] = v;
        }
      }
    }
  }
}

// XCD-local, reduce-free sampler.
// Block = one (b,h) plane x 64 queries; plane = blockIdx&15 -> each XCD's L2
// sees ~2 planes (1.7MB) of vproj.
// Phase A: 1024 (ql,lp) descriptor tasks, fused 16-wide softmax; packed 8B
// {base:int, half2(w0,w1)} into dpack[lp][yi][ql] (padded, conflict-free).
// Phase B: wave = [16 queries][4 ch-slices]; each lane serially accumulates
// all 64 gathers for its own 8 channels -> no cross-lane reduce at all.
__global__ __launch_bounds__(256) void sample_k(
    const __hip_bfloat16* __restrict__ vproj,
    const __hip_bfloat16* __restrict__ offaw,
    const float* __restrict__ refp,
    __hip_bfloat16* __restrict__ interm)
{
  __shared__ u32x2 dpack[16][2][65];   // 16.6 KB; [lp][yi][ql] (+1 pad on ql)
  const int plane = blockIdx.x & 15;
  const int chunk = blockIdx.x >> 4;
  const int b = plane >> 3, h = plane & 7;
  const int q0 = chunk * 64;
  const int tid = threadIdx.x;
  const int dims[4]   = {100, 50, 25, 13};
  const int starts[4] = {0, 10000, 12500, 13125};

#pragma unroll
  for (int it = 0; it < 4; it++) {
    const int task = it * 256 + tid;
    const int ql = task >> 4, lp = task & 15;
    const int l = lp >> 2;
    const int lw = dims[l];
    int q = q0 + ql; if (q >= NQ) q = NQ - 1;   // clamped read; store guarded later
    const size_t row = (size_t)b * NQ + q;
    unsigned int oxy = *(const unsigned int*)((const unsigned short*)offaw + row * 384 + h * 32 + lp * 2);
    float offx = __uint_as_float(oxy << 16);
    float offy = __uint_as_float(oxy & 0xffff0000u);
    float logit = __bfloat162float(offaw[row * 384 + 256 + h * 16 + lp]);
    float2 rp = *(const float2*)(refp + (row * 4 + l) * 2);
    float gx = rp.x * (float)lw + offx - 0.5f;
    float gy = rp.y * (float)lw + offy - 0.5f;
    float mx = logit;
#pragma unroll
    for (int d = 1; d < 16; d <<= 1) mx = fmaxf(mx, __shfl_xor(mx, d));
    float e = __expf(logit - mx);
    float ssum = e;
#pragma unroll
    for (int d = 1; d < 16; d <<= 1) ssum += __shfl_xor(ssum, d);
    float aw = e / ssum;

    float xf = floorf(gx), yf = floorf(gy);
    int x0 = (int)xf, y0 = (int)yf;
    float wx = gx - xf, wy = gy - yf;
    int bx = min(max(x0, 0), lw - 2);
    bool lxv = (x0 >= 0) & (x0 < lw);
    bool rxv = (x0 + 1 >= 0) & (x0 + 1 < lw);
    float wl = 1.f - wx, wr = wx;
    float ws0 = (lxv && x0 == bx     ? wl : 0.f) + (rxv && x0 + 1 == bx     ? wr : 0.f);
    float ws1 = (lxv && x0 == bx + 1 ? wl : 0.f) + (rxv && x0 + 1 == bx + 1 ? wr : 0.f);
    const int pbase = (b * Hh + h) * NQ + starts[l];
#pragma unroll
    for (int yi = 0; yi < 2; yi++) {
      int yc = y0 + yi;
      bool yv = (yc >= 0) & (yc < lw);
      int ycl = min(max(yc, 0), lw - 1);
      float wyt = (yi ? wy : 1.f - wy) * aw * (yv ? 1.f : 0.f);
      __half h0 = __float2half(ws0 * wyt);
      __half h1 = __float2half(ws1 * wyt);
      unsigned int pw = (unsigned int)(*(unsigned short*)&h0)
                      | ((unsigned int)(*(unsigned short*)&h1) << 16);
      u32x2 pk; pk[0] = (unsigned int)(pbase + ycl * lw + bx); pk[1] = pw;
      dpack[lp][yi][ql] = pk;
    }
  }
  __syncthreads();

  const int wv = tid >> 6, lane = tid & 63;
  const int qsub = lane >> 2, c = lane & 3;
  const int ql = wv * 16 + qsub;
  const char* vpc = (const char*)vproj + c * 16;
  f32x2 a2[4] = {};
#pragma unroll 4
  for (int lp = 0; lp < 16; lp++) {
#pragma unroll
    for (int yi = 0; yi < 2; yi++) {
      const u32x2 d = dpack[lp][yi][ql];
#pragma unroll
      for (int r = 0; r < 2; r++) {
        unsigned short hw = (unsigned short)(r ? (d[1] >> 16) : (d[1] & 0xffffu));
        const float w = __half2float(*(const __half*)&hw);
        const u32x4 u = *(const u32x4*)(vpc + ((size_t)(d[0] + r) << 6));
        const f32x2 wb = {w, w};
#pragma unroll
        for (int j = 0; j < 4; j++) {
          f32x2 v2 = { __uint_as_float(u[j] << 16), __uint_as_float(u[j] & 0xffff0000u) };
          a2[j] += v2 * wb;
        }
      }
    }
  }
  const int q = q0 + ql;
  if (q < NQ) {
    unsigned int up[4];
#pragma unroll
    for (int j = 0; j < 4; j++) {
      unsigned int b0 = (unsigned int)(unsigned short)bf16_of(a2[j][0]);
      unsigned int b1 = (unsigned int)(unsigned short)bf16_of(a2[j][1]);
      up[j] = (b1 << 16) | b0;
    }
    u32x4 pk = { up[0], up[1], up[2], up[3] };
    *(u32x4*)((unsigned short*)interm + ((size_t)b * NQ + q) * 256 + h * 32 + c * 8) = pk;
  }
}

extern "C" void kernel_launch(void* const* d_in, const int* in_sizes, int n_in,
                              void* d_out, int out_size, void* d_ws, size_t ws_size,
                              hipStream_t stream)
{
  const float* query = (const float*)d_in[0];
  const float* refp  = (const float*)d_in[1];
  const float* value = (const float*)d_in[2];
  // d_in[3] = spatial_shapes (static, hardcoded)
  const float* Wso = (const float*)d_in[4];
  const float* bso = (const float*)d_in[5];
  const float* Waw = (const float*)d_in[6];
  const float* baw = (const float*)d_in[7];
  const float* Wv  = (const float*)d_in[8];
  const float* bv  = (const float*)d_in[9];
  const float* Wo  = (const float*)d_in[10];
  const float* bo  = (const float*)d_in[11];

  char* ws = (char*)d_ws;
  __hip_bfloat16* vproj  = (__hip_bfloat16*)ws;                 // 13,613,056 B
  __hip_bfloat16* offaw  = (__hip_bfloat16*)(ws + 13613056);    // 20,419,584 B
  __hip_bfloat16* interm = (__hip_bfloat16*)(ws + 34032640);    // 13,613,056 B
  short* WvT = (short*)(ws + 47645696);                         //    131,072 B
  short* WqT = (short*)(ws + 47776768);                         //    196,608 B
  short* WoT = (short*)(ws + 47973376);                         //    131,072 B
  float* bq  = (float*)(ws + 48104448);                         //      1,536 B
  float* out = (float*)d_out;

  dim3 blk(256);
  prep_k<<<dim3(896), blk, 0, stream>>>(Wv, Wso, Waw, Wo, bso, baw, WvT, WqT, WoT, bq);
  gemm_k<0, 4><<<dim3(4 * 416), blk, 0, stream>>>(value, WvT, bv, vproj);
  gemm_k<1, 6><<<dim3(6 * 416), blk, 0, stream>>>(query, WqT, bq, offaw);
  sample_k<<<dim3(16 * 208), blk, 0, stream>>>(vproj, offaw, refp, interm);
  gemm_k<3, 4><<<dim3(4 * 416), blk, 0, stream>>>(interm, WoT, bo, out);
}

// Round 8
// 100.312 us; speedup vs baseline: 1.9719x; 1.0436x over previous
//
#include <hip/hip_runtime.h>
#include <hip/hip_bf16.h>
#include <hip/hip_fp16.h>

typedef short s16x8 __attribute__((ext_vector_type(8)));
typedef float f32x4 __attribute__((ext_vector_type(4)));
typedef float f32x2 __attribute__((ext_vector_type(2)));
typedef unsigned int u32x4 __attribute__((ext_vector_type(4)));

constexpr int Bb = 2, NQ = 13294, Hh = 8, HD = 32;
constexpr int Mrows = Bb * NQ; // 26588

__device__ inline short bf16_of(float f) {
  __hip_bfloat16 h = __float2bfloat16(f);
  return *reinterpret_cast<short*>(&h);
}

// One-time weight prep: WT[n][k] = bf16(W[k][n]) for Wv, {Wso|Waw} fused, Wo;
// bq = concat(bso, baw) fp32. 229,376 tasks = 896 blocks x 256.
__global__ __launch_bounds__(256) void prep_k(
    const float* __restrict__ Wv, const float* __restrict__ Wso,
    const float* __restrict__ Waw, const float* __restrict__ Wo,
    const float* __restrict__ bso, const float* __restrict__ baw,
    short* __restrict__ WvT, short* __restrict__ WqT, short* __restrict__ WoT,
    float* __restrict__ bq)
{
  const int id = blockIdx.x * 256 + threadIdx.x;
  if (id < 384) bq[id] = id < 256 ? bso[id] : baw[id - 256];
  if (id < 65536) {
    int n = id >> 8, k = id & 255;
    WvT[id] = bf16_of(Wv[k * 256 + n]);
  } else if (id < 163840) {
    int t = id - 65536, n = t >> 8, k = t & 255;
    WqT[t] = bf16_of(n < 256 ? Wso[k * 256 + n] : Waw[k * 128 + (n - 256)]);
  } else {
    int t = id - 163840, n = t >> 8, k = t & 255;
    WoT[t] = bf16_of(Wo[k * 256 + n]);
  }
}

// Pipelined 128x64-tile GEMM body: C = A[M,256] @ WT^T + bias.
// Double-buffered LDS, register prefetch of tile t+1 issued before MFMA of t,
// ONE barrier per K-step, 8 MFMA/wave/step. 208 row-panels = 8 XCDs x 26:
// xcd = wg&7 owns 26 contiguous panels x NT col-tiles (col-fast) for L2 reuse.
// MODE 0: A fp32 -> bf16 scatter vproj[B][H][NQ][HD] (NT=4)
// MODE 1: A fp32 -> bf16 offaw[row*384+col], fused Wso|Waw WT[384][256] (NT=6)
// MODE 3: A bf16 -> fp32 out[row*256+col] (NT=4)
template<int MODE>
__device__ __forceinline__ void gemm_body(
    const void* __restrict__ Araw, const short* __restrict__ WT,
    const float* __restrict__ bias, void* __restrict__ outraw,
    int wg, short (* __restrict__ As)[128][40], short (* __restrict__ Bs)[64][40])
{
  constexpr int NT = (MODE == 1) ? 6 : 4;
  const int xcd = wg & 7, local = wg >> 3;
  const int row0 = (xcd * 26 + local / NT) * 128;
  const int col0 = (local % NT) * 64;
  const int tid = threadIdx.x, lane = tid & 63, wave = tid >> 6;

  f32x4 acc[2][4] = {};

  int arow[2], aq[2], ga[2];
#pragma unroll
  for (int it = 0; it < 2; it++) {
    int task = it * 256 + tid;
    arow[it] = task >> 2; aq[it] = task & 3;
    ga[it] = min(row0 + arow[it], Mrows - 1);
  }
  const int bcol = tid >> 2, bqd = tid & 3;

  f32x4 a0[2], a1[2]; s16x8 abf[2]; s16x8 breg;

  auto load_tile = [&](int kt) {
#pragma unroll
    for (int it = 0; it < 2; it++) {
      if constexpr (MODE == 3) {
        abf[it] = *(const s16x8*)((const short*)Araw + (size_t)ga[it] * 256 + kt + aq[it] * 8);
      } else {
        const float* A = (const float*)Araw;
        a0[it] = *(const f32x4*)(A + (size_t)ga[it] * 256 + kt + aq[it] * 8);
        a1[it] = *(const f32x4*)(A + (size_t)ga[it] * 256 + kt + aq[it] * 8 + 4);
      }
    }
    breg = *(const s16x8*)(WT + (size_t)(col0 + bcol) * 256 + kt + bqd * 8);
  };

  auto write_tile = [&](int buf) {
#pragma unroll
    for (int it = 0; it < 2; it++) {
      s16x8 av;
      if constexpr (MODE == 3) { av = abf[it]; }
      else {
#pragma unroll
        for (int i = 0; i < 4; i++) { av[i] = bf16_of(a0[it][i]); av[4 + i] = bf16_of(a1[it][i]); }
      }
      *(s16x8*)(&As[buf][arow[it]][aq[it] * 8]) = av;
    }
    *(s16x8*)(&Bs[buf][bcol][bqd * 8]) = breg;
  };

  load_tile(0);
  const int fr = lane & 15, kg = lane >> 4;
#pragma unroll
  for (int t = 0; t < 8; t++) {
    const int buf = t & 1;
    write_tile(buf);
    __syncthreads();
    if (t < 7) load_tile((t + 1) * 32);   // in flight across the MFMA below
    s16x8 bfr[4], afr[2];
#pragma unroll
    for (int n = 0; n < 4; n++) bfr[n] = *(const s16x8*)(&Bs[buf][n * 16 + fr][kg * 8]);
#pragma unroll
    for (int m = 0; m < 2; m++) afr[m] = *(const s16x8*)(&As[buf][wave * 32 + m * 16 + fr][kg * 8]);
#pragma unroll
    for (int m = 0; m < 2; m++)
#pragma unroll
      for (int n = 0; n < 4; n++)
        acc[m][n] = __builtin_amdgcn_mfma_f32_16x16x32_bf16(afr[m], bfr[n], acc[m][n], 0, 0, 0);
  }

  // D mapping (verified): col = lane&15, row-in-frag = kg*4 + reg
#pragma unroll
  for (int n = 0; n < 4; n++) {
    const int colL = col0 + n * 16 + fr;
    const float bvf = bias[colL];
#pragma unroll
    for (int m = 0; m < 2; m++) {
#pragma unroll
      for (int r = 0; r < 4; r++) {
        const int rowL = row0 + wave * 32 + m * 16 + kg * 4 + r;
        if (rowL < Mrows) {
          float v = acc[m][n][r] + bvf;
          if constexpr (MODE == 0) {
            int b = rowL >= NQ, nn = rowL - b * NQ;
            int h = colL >> 5, c = colL & 31;
            ((__hip_bfloat16*)outraw)[(((size_t)b * Hh + h) * NQ + nn) * HD + c] = __float2bfloat16(v);
          } else if constexpr (MODE == 1) {
            ((__hip_bfloat16*)outraw)[(size_t)rowL * 384 + colL] = __float2bfloat16(v);
          } else {
            ((float*)outraw)[(size_t)rowL * 256 + colL] = v;
          }
        }
      }
    }
  }
}

// Fused value-proj + query-proj (independent GEMMs, one launch).
__global__ __launch_bounds__(256) void gemm01_k(
    const float* __restrict__ value, const float* __restrict__ query,
    const short* __restrict__ WvT, const short* __restrict__ WqT,
    const float* __restrict__ bv, const float* __restrict__ bq,
    __hip_bfloat16* __restrict__ vproj, __hip_bfloat16* __restrict__ offaw)
{
  __shared__ short As[2][128][40];
  __shared__ short Bs[2][64][40];
  const int wg = blockIdx.x;
  if (wg < 832) gemm_body<0>(value, WvT, bv, vproj, wg, As, Bs);
  else          gemm_body<1>(query, WqT, bq, offaw, wg - 832, As, Bs);
}

__global__ __launch_bounds__(256) void gemm3_k(
    const short* __restrict__ interm, const short* __restrict__ WoT,
    const float* __restrict__ bo, float* __restrict__ out)
{
  __shared__ short As[2][128][40];
  __shared__ short Bs[2][64][40];
  gemm_body<3>(interm, WoT, bo, out, blockIdx.x, As, Bs);
}

// XCD-local, reduce-free sampler.
// Block = one (b,h) plane x 64 queries; plane = blockIdx&15 -> each XCD's L2
// sees ~2 planes (1.7MB) of vproj.
// Phase A: 1024 (ql,lp) descriptor tasks, fused 16-wide softmax; writes
// dbase[lp][yi][ql] (int) + dwgt[lp][yi][ql] (f32x2) - f32 weights kill the
// per-iter half->float cvt; one 64-bit addr per (lp,yi), r=1 load folds to
// offset:64.
// Phase B: wave = [16 queries][4 ch-slices]; each lane serially accumulates
// all 64 gathers for its own 8 channels -> no cross-lane reduce.
__global__ __launch_bounds__(256) void sample_k(
    const __hip_bfloat16* __restrict__ vproj,
    const __hip_bfloat16* __restrict__ offaw,
    const float* __restrict__ refp,
    __hip_bfloat16* __restrict__ interm)
{
  __shared__ int   dbase[16][2][65];   //  8,320 B
  __shared__ f32x2 dwgt[16][2][65];    // 16,640 B
  const int plane = blockIdx.x & 15;
  const int chunk = blockIdx.x >> 4;
  const int b = plane >> 3, h = plane & 7;
  const int q0 = chunk * 64;
  const int tid = threadIdx.x;
  const int dims[4]   = {100, 50, 25, 13};
  const int starts[4] = {0, 10000, 12500, 13125};

#pragma unroll
  for (int it = 0; it < 4; it++) {
    const int task = it * 256 + tid;
    const int ql = task >> 4, lp = task & 15;
    const int l = lp >> 2;
    const int lw = dims[l];
    int q = q0 + ql; if (q >= NQ) q = NQ - 1;   // clamped read; store guarded later
    const size_t row = (size_t)b * NQ + q;
    unsigned int oxy = *(const unsigned int*)((const unsigned short*)offaw + row * 384 + h * 32 + lp * 2);
    float offx = __uint_as_float(oxy << 16);
    float offy = __uint_as_float(oxy & 0xffff0000u);
    float logit = __bfloat162float(offaw[row * 384 + 256 + h * 16 + lp]);
    float2 rp = *(const float2*)(refp + (row * 4 + l) * 2);
    float gx = rp.x * (float)lw + offx - 0.5f;
    float gy = rp.y * (float)lw + offy - 0.5f;
    float mx = logit;
#pragma unroll
    for (int d = 1; d < 16; d <<= 1) mx = fmaxf(mx, __shfl_xor(mx, d));
    float e = __expf(logit - mx);
    float ssum = e;
#pragma unroll
    for (int d = 1; d < 16; d <<= 1) ssum += __shfl_xor(ssum, d);
    float aw = e / ssum;

    float xf = floorf(gx), yf = floorf(gy);
    int x0 = (int)xf, y0 = (int)yf;
    float wx = gx - xf, wy = gy - yf;
    int bx = min(max(x0, 0), lw - 2);
    bool lxv = (x0 >= 0) & (x0 < lw);
    bool rxv = (x0 + 1 >= 0) & (x0 + 1 < lw);
    float wl = 1.f - wx, wr = wx;
    float ws0 = (lxv && x0 == bx     ? wl : 0.f) + (rxv && x0 + 1 == bx     ? wr : 0.f);
    float ws1 = (lxv && x0 == bx + 1 ? wl : 0.f) + (rxv && x0 + 1 == bx + 1 ? wr : 0.f);
    const int pbase = (b * Hh + h) * NQ + starts[l];
#pragma unroll
    for (int yi = 0; yi < 2; yi++) {
      int yc = y0 + yi;
      bool yv = (yc >= 0) & (yc < lw);
      int ycl = min(max(yc, 0), lw - 1);
      float wyt = (yi ? wy : 1.f - wy) * aw * (yv ? 1.f : 0.f);
      dbase[lp][yi][ql] = pbase + ycl * lw + bx;
      f32x2 w2; w2[0] = ws0 * wyt; w2[1] = ws1 * wyt;
      dwgt[lp][yi][ql] = w2;
    }
  }
  __syncthreads();

  const int wv = tid >> 6, lane = tid & 63;
  const int qsub = lane >> 2, c = lane & 3;
  const int ql = wv * 16 + qsub;
  const char* vpc = (const char*)vproj + c * 16;
  f32x2 a2[4] = {};
#pragma unroll 4
  for (int lp = 0; lp < 16; lp++) {
#pragma unroll
    for (int yi = 0; yi < 2; yi++) {
      const int d0 = dbase[lp][yi][ql];
      const f32x2 w2 = dwgt[lp][yi][ql];
      const char* p = vpc + ((size_t)d0 << 6);
      const u32x4 u0 = *(const u32x4*)p;
      const u32x4 u1 = *(const u32x4*)(p + 64);   // offset:64, same base reg
      const f32x2 wb0 = {w2[0], w2[0]};
      const f32x2 wb1 = {w2[1], w2[1]};
#pragma unroll
      for (int j = 0; j < 4; j++) {
        f32x2 v0 = { __uint_as_float(u0[j] << 16), __uint_as_float(u0[j] & 0xffff0000u) };
        f32x2 v1 = { __uint_as_float(u1[j] << 16), __uint_as_float(u1[j] & 0xffff0000u) };
        a2[j] += v0 * wb0;
        a2[j] += v1 * wb1;
      }
    }
  }
  const int q = q0 + ql;
  if (q < NQ) {
    unsigned int up[4];
#pragma unroll
    for (int j = 0; j < 4; j++) {
      unsigned int b0 = (unsigned int)(unsigned short)bf16_of(a2[j][0]);
      unsigned int b1 = (unsigned int)(unsigned short)bf16_of(a2[j][1]);
      up[j] = (b1 << 16) | b0;
    }
    u32x4 pk = { up[0], up[1], up[2], up[3] };
    *(u32x4*)((unsigned short*)interm + ((size_t)b * NQ + q) * 256 + h * 32 + c * 8) = pk;
  }
}

extern "C" void kernel_launch(void* const* d_in, const int* in_sizes, int n_in,
                              void* d_out, int out_size, void* d_ws, size_t ws_size,
                              hipStream_t stream)
{
  const float* query = (const float*)d_in[0];
  const float* refp  = (const float*)d_in[1];
  const float* value = (const float*)d_in[2];
  // d_in[3] = spatial_shapes (static, hardcoded)
  const float* Wso = (const float*)d_in[4];
  const float* bso = (const float*)d_in[5];
  const float* Waw = (const float*)d_in[6];
  const float* baw = (const float*)d_in[7];
  const float* Wv  = (const float*)d_in[8];
  const float* bv  = (const float*)d_in[9];
  const float* Wo  = (const float*)d_in[10];
  const float* bo  = (const float*)d_in[11];

  char* ws = (char*)d_ws;
  __hip_bfloat16* vproj  = (__hip_bfloat16*)ws;                 // 13,613,056 B
  __hip_bfloat16* offaw  = (__hip_bfloat16*)(ws + 13613056);    // 20,419,584 B
  __hip_bfloat16* interm = (__hip_bfloat16*)(ws + 34032640);    // 13,613,056 B
  short* WvT = (short*)(ws + 47645696);                         //    131,072 B
  short* WqT = (short*)(ws + 47776768);                         //    196,608 B
  short* WoT = (short*)(ws + 47973376);                         //    131,072 B
  float* bq  = (float*)(ws + 48104448);                         //      1,536 B
  float* out = (float*)d_out;

  dim3 blk(256);
  prep_k<<<dim3(896), blk, 0, stream>>>(Wv, Wso, Waw, Wo, bso, baw, WvT, WqT, WoT, bq);
  gemm01_k<<<dim3(832 + 1248), blk, 0, stream>>>(value, query, WvT, WqT, bv, bq, vproj, offaw);
  sample_k<<<dim3(16 * 208), blk, 0, stream>>>(vproj, offaw, refp, interm);
  gemm3_k<<<dim3(832), blk, 0, stream>>>((const short*)interm, WoT, bo, out);
}